// Round 4
// baseline (720.474 us; speedup 1.0000x reference)
//
#include <hip/hip_runtime.h>
#include <hip/hip_cooperative_groups.h>

namespace cg = cooperative_groups;

typedef unsigned short ushort_t;
typedef unsigned int uint_t;
typedef __attribute__((ext_vector_type(8))) short short8;
typedef __attribute__((ext_vector_type(4))) float float4v;

constexpr int Bb = 2, Tt = 12, Nn = 50000, Hh = 16, Ee = 800000;
constexpr int T1 = 10, T2 = 8;
constexpr int F = 320;     // features per node, layout f = t*32 + b*16 + h
constexpr int NP = 50176;  // padded node stride for per-XCD deg/cnt copies
constexpr int NXCD = 8;    // MI355X XCD count
constexpr int CAP8 = 16;   // per-XCD bucket capacity per dst (8*16=128 total)

#define DEV __device__ __forceinline__

DEV float bf2f(ushort_t u) { return __uint_as_float(((uint_t)u) << 16); }
DEV ushort_t f2bf(float f) {
  uint_t u = __float_as_uint(f);
  u += 0x7fffu + ((u >> 16) & 1u);  // RNE
  return (ushort_t)(u >> 16);
}
DEV float blo(uint_t u) { return __uint_as_float(u << 16); }
DEV float bhi(uint_t u) { return __uint_as_float(u & 0xffff0000u); }
DEV float sigm(float x) { return 1.0f / (1.0f + __expf(-x)); }

// Hardware XCD id (0..7 on MI355X). Wave-uniform. Used only as a partition
// hint — correctness holds for ANY value in [0,8).
DEV int xcc_id() {
  int x;
  asm volatile("s_getreg_b32 %0, hwreg(HW_REG_XCC_ID)" : "=s"(x));
  return x & (NXCD - 1);
}

// Flag-aware loads: flags[0]=1 -> floats stored as bf16; flags[1]=1 -> ints are int64.
DEV float loadF(const void* p, int j, int isb) {
  return isb ? bf2f(((const ushort_t*)p)[j]) : ((const float*)p)[j];
}
DEV int loadI(const void* p, long long j, int is64) {
  return is64 ? (int)(((const long long*)p)[j]) : ((const int*)p)[j];
}

// ---------------------------------------------------------------------------
// Weight prep + dtype detection + workspace zeroing + tc2 B-fragment packing.
// Kept as a SEPARATE kernel: its boundary flushes the zeroed deg8/cnt8 lines
// to the memory side before k_mega's memory-side atomics RMW them (fusing
// this phase would race dirty zero-lines in L2 against memory-side atomics).
// W layout (float offsets):
//  tc1: Pw 0(48) Pb 48 Qw 64 Qb 112 Rw 128 Rb 176
//  tc2: Pw 192(768) Pb 960 Qw 976 Qb 1744 Rw 1760 Rb 2528
//  cheb: W0 2544(256) W1 2800(256) b 3056(16);  lin: W 3072(32) b 3104(2)
// Bf: tc2 weights as mfma_16x16x32_bf16 B-fragments (K=48 zero-padded to 64).
// Zeroing covers deg8 (8*NP u32) + cnt8 (8*NP i32) = 16*NP contiguous words.
// ---------------------------------------------------------------------------
__global__ void k_wprep(const void* ew, const void* ei,
                        const void* t1Pw, const void* t1Pb,
                        const void* t1Qw, const void* t1Qb,
                        const void* t1Rw, const void* t1Rb,
                        const void* t2Pw, const void* t2Pb,
                        const void* t2Qw, const void* t2Qb,
                        const void* t2Rw, const void* t2Rb,
                        const void* chw, const void* chb,
                        const void* lw, const void* lb,
                        int* flags, float* W, ushort_t* Bf, uint_t* zero_base) {
  int gid = blockIdx.x * 256 + threadIdx.x;
  if (gid < 16 * NP) zero_base[gid] = 0u;
  if (blockIdx.x != 0) return;

  __shared__ int sflags[2];
  int tid = threadIdx.x;
  if (tid < 64) {
    int lane = tid;
    const ushort_t* u = (const ushort_t*)ew;
    int cnt = 0;
    for (int j = lane; j < 512; j += 64) cnt += (u[j] < 0x3F80u) ? 1 : 0;
#pragma unroll
    for (int d = 32; d; d >>= 1) cnt += __shfl_xor(cnt, d, 64);
    const int* e32 = (const int*)ei;
    int even_nz = 0, odd_nz = 0;
    for (int j = 2 * lane; j < 256; j += 128) {
      even_nz |= (e32[j] != 0);
      odd_nz |= (e32[j + 1] != 0);
    }
    unsigned long long be = __ballot(even_nz), bo = __ballot(odd_nz);
    if (lane == 0) {
      int f0 = (cnt >= 450) ? 1 : 0;
      int f1 = (bo == 0ull && be != 0ull) ? 1 : 0;
      sflags[0] = f0; sflags[1] = f1;
      flags[0] = f0; flags[1] = f1;
    }
  }
  __syncthreads();
  int isb = sflags[0];
#define CVT(src, off, n) for (int j = tid; j < (n); j += 256) W[(off) + j] = loadF(src, j, isb);
  CVT(t1Pw, 0, 48)   CVT(t1Pb, 48, 16)
  CVT(t1Qw, 64, 48)  CVT(t1Qb, 112, 16)
  CVT(t1Rw, 128, 48) CVT(t1Rb, 176, 16)
  CVT(t2Pw, 192, 768)  CVT(t2Pb, 960, 16)
  CVT(t2Qw, 976, 768)  CVT(t2Qb, 1744, 16)
  CVT(t2Rw, 1760, 768) CVT(t2Rb, 2528, 16)
  CVT(chw, 2544, 512)  CVT(chb, 3056, 16)
  CVT(lw, 3072, 32)    CVT(lb, 3104, 2)
#undef CVT
  // Pack tc2 weights into B-fragments (reads inputs directly; no W dependency).
  for (int i = tid; i < 3072; i += 256) {
    int j = i & 7, lane = (i >> 3) & 63, s = (i >> 9) & 1, tau = i >> 10;
    int kap = s * 32 + ((lane >> 4) << 3) + j;
    int nsub = lane & 15;
    ushort_t v = 0;
    if (kap < 48) {
      int kk = kap >> 4, c = kap & 15;
      const void* src = (tau == 0) ? t2Pw : (tau == 1) ? t2Qw : t2Rw;
      v = f2bf(loadF(src, kk * 256 + c * 16 + nsub, isb));
    }
    Bf[i] = v;
  }
}

// ---------------------------------------------------------------------------
// R18 MEGA KERNEL: fused {pre | dis | agg | tc2h} with grid-wide barriers.
// Rationale: R1's kernel sum (~194 us) vs dur_us (283) leaves ~85-90 us in
// kernel-boundary overhead (drain + L2 flush/inv + launch). Phase bodies are
// the R1-proven forms (tc1 per-(b,t,n) thread reverted — R17's fat-thread
// version spilled: VGPR 40->20, VALUBusy 16->57%). __threadfence() before
// each grid.sync() gives device-scope release (wbl2) so xfh/deg8/h2 written
// on one XCD are visible to readers on other XCDs after the barrier.
// ---------------------------------------------------------------------------
__global__ __launch_bounds__(256, 4) void k_mega(
    const void* __restrict__ x, const void* __restrict__ ei,
    const void* __restrict__ ew, const float* __restrict__ W,
    const int* __restrict__ flags, ushort_t* xfh, uint_t* deg8,
    int* cnt8, uint_t* ecv8, ushort_t* h2,
    const ushort_t* __restrict__ Bf, float* out) {
  cg::grid_group grid = cg::this_grid();
  __shared__ float sh[4][640];  // per wave (agg phase): [0..319]=agg, [320..639]=x
  const int tid = threadIdx.x;
  const int gid0 = blockIdx.x * 256 + tid;
  const int GS = gridDim.x * 256;
  const int isb = flags[0], is64 = flags[1];
  const int wid = tid >> 6, lane = tid & 63;

  // ===== phase 1: fused tc1 + degree accumulation + bucket scatter =====
  {
    const int xcd = xcc_id();
    for (int id = gid0; id < Bb * T1 * Nn; id += GS) {
      if (id < Ee) {
        int s = loadI(ei, id, is64), d = loadI(ei, (long long)Ee + id, is64);
        float w = loadF(ew, id, isb);
        uint_t wq = __float2uint_rn(w * 16777216.0f);  // w * 2^24, w in [0,1]
        __hip_atomic_fetch_add(&deg8[xcd * NP + s], wq,
                               __ATOMIC_RELAXED, __HIP_MEMORY_SCOPE_WORKGROUP);
        int pos = __hip_atomic_fetch_add(&cnt8[xcd * NP + d], 1,
                                         __ATOMIC_RELAXED, __HIP_MEMORY_SCOPE_WORKGROUP);
        if (pos < CAP8)
          ecv8[((size_t)xcd * Nn + d) * CAP8 + pos] =
              ((uint_t)s << 16) | (uint_t)f2bf(w);
      }
      {
        int n = id % Nn;
        int bt = id / Nn;
        int t = bt % T1, b = bt / T1;
        float x0 = loadF(x, (b * Tt + t + 0) * Nn + n, isb);
        float x1 = loadF(x, (b * Tt + t + 1) * Nn + n, isb);
        float x2 = loadF(x, (b * Tt + t + 2) * Nn + n, isb);
        ushort_t g[16];
#pragma unroll
        for (int h = 0; h < 16; ++h) {
          float p = W[48 + h] + x0 * W[0 + h] + x1 * W[16 + h] + x2 * W[32 + h];
          float q = W[112 + h] + x0 * W[64 + h] + x1 * W[80 + h] + x2 * W[96 + h];
          float r = W[176 + h] + x0 * W[128 + h] + x1 * W[144 + h] + x2 * W[160 + h];
          g[h] = f2bf(fmaxf(fmaf(p, sigm(q), r), 0.0f));
        }
        uint_t u[8];
#pragma unroll
        for (int j = 0; j < 8; ++j)
          u[j] = (uint_t)g[2 * j] | ((uint_t)g[2 * j + 1] << 16);
        uint4* dst = (uint4*)(xfh + (size_t)n * F + t * 32 + b * 16);
        dst[0] = make_uint4(u[0], u[1], u[2], u[3]);
        dst[1] = make_uint4(u[4], u[5], u[6], u[7]);
      }
    }
  }
  __threadfence();
  grid.sync();

  // ===== phase 2: dis = 1/sqrt(deg), in place into copy 0 (as float) =====
  for (int i = gid0; i < Nn; i += GS) {
    uint_t v = 0;
#pragma unroll
    for (int j = 0; j < 8; ++j) v += deg8[j * NP + i];
    float f = (float)v * (1.0f / 16777216.0f);
    ((float*)deg8)[i] = (v > 0u) ? (1.0f / sqrtf(fmaxf(f, 1e-12f))) : 0.0f;
  }
  __threadfence();
  grid.sync();

  // ===== phase 3: SpMM gather + Cheb combine + relu (one wave per dst) =====
  {
    const float* dis = (const float*)deg8;
    const uint2* xf2 = (const uint2*)xfh;
    const int l16 = 64 + (lane & 15);
    for (int gw = blockIdx.x * 4 + wid; gw < Nn; gw += gridDim.x * 4) {
      // Merge 8 per-XCD sub-lists: prefix over counts, lane -> (xcd, slot).
      int myx = 0, slot = lane, tot = 0;
#pragma unroll
      for (int xx = 0; xx < NXCD; ++xx) {
        int c = min(cnt8[xx * NP + gw], CAP8);
        if (lane >= tot) { myx = xx; slot = lane - tot; }
        tot += c;
      }
      int deg = min(tot, 64);
      float a0 = 0.f, a1 = 0.f, a2 = 0.f, a3 = 0.f;
      float c0 = 0.f, c1 = 0.f, c2 = 0.f, c3 = 0.f;

#define ACC(v, p, q)                                                          \
  a0 = fmaf(v, blo(p.x), a0); a1 = fmaf(v, bhi(p.x), a1);                     \
  a2 = fmaf(v, blo(p.y), a2); a3 = fmaf(v, bhi(p.y), a3);                     \
  c0 = fmaf(v, blo(q.x), c0); c1 = fmaf(v, bhi(q.x), c1);                     \
  c2 = fmaf(v, blo(q.y), c2); c3 = fmaf(v, bhi(q.y), c3);

      int colv = 0;    // BYTE offset of this lane's src row
      int valv_i = 0;  // bits of val (for readlane broadcast)
      if (lane < deg) {
        uint_t t = ecv8[((size_t)myx * Nn + gw) * CAP8 + slot];
        int src = t >> 16;
        colv = src * (F * 2);
        valv_i = __float_as_int(bf2f((ushort_t)(t & 0xffffu)) * dis[src]);
      }
      const char* xb = (const char*)xf2;
      int e = 0;
      for (; e + 4 <= deg; e += 4) {
        int b0 = __builtin_amdgcn_readlane(colv, e + 0);
        int b1 = __builtin_amdgcn_readlane(colv, e + 1);
        int b2 = __builtin_amdgcn_readlane(colv, e + 2);
        int b3 = __builtin_amdgcn_readlane(colv, e + 3);
        float v0 = __int_as_float(__builtin_amdgcn_readlane(valv_i, e + 0));
        float v1 = __int_as_float(__builtin_amdgcn_readlane(valv_i, e + 1));
        float v2 = __int_as_float(__builtin_amdgcn_readlane(valv_i, e + 2));
        float v3 = __int_as_float(__builtin_amdgcn_readlane(valv_i, e + 3));
        const uint2* t0 = (const uint2*)(xb + b0);
        const uint2* t1 = (const uint2*)(xb + b1);
        const uint2* t2 = (const uint2*)(xb + b2);
        const uint2* t3 = (const uint2*)(xb + b3);
        uint2 p0 = t0[lane], q0 = t0[l16];
        uint2 p1 = t1[lane], q1 = t1[l16];
        uint2 p2 = t2[lane], q2 = t2[l16];
        uint2 p3 = t3[lane], q3 = t3[l16];
        ACC(v0, p0, q0) ACC(v1, p1, q1) ACC(v2, p2, q2) ACC(v3, p3, q3)
      }
      for (; e < deg; ++e) {
        int b = __builtin_amdgcn_readlane(colv, e);
        float v = __int_as_float(__builtin_amdgcn_readlane(valv_i, e));
        const uint2* tp = (const uint2*)(xb + b);
        uint2 p = tp[lane], q = tp[l16];
        ACC(v, p, q)
      }
#undef ACC

      float nd = -dis[gw];  // wave-uniform
      float* sa = sh[wid];
      float* sx = sh[wid] + 320;
      const uint2* xrow = xf2 + (size_t)gw * 80;
      uint2 xp = xrow[lane], xq = xrow[l16];
      ((float4*)sa)[lane] = make_float4(a0 * nd, a1 * nd, a2 * nd, a3 * nd);
      ((float4*)sx)[lane] = make_float4(blo(xp.x), bhi(xp.x), blo(xp.y), bhi(xp.y));
      if (lane < 16) {
        ((float4*)sa)[64 + lane] = make_float4(c0 * nd, c1 * nd, c2 * nd, c3 * nd);
        ((float4*)sx)[64 + lane] = make_float4(blo(xq.x), bhi(xq.x), blo(xq.y), bhi(xq.y));
      }
      __builtin_amdgcn_wave_barrier();  // wave-private LDS: block reordering only
      int h = lane & 15;
      float w0[16], w1[16];
#pragma unroll
      for (int c = 0; c < 16; ++c) {
        w0[c] = W[2544 + c * 16 + h];
        w1[c] = W[2800 + c * 16 + h];
      }
      float bias = W[3056 + h];
      ushort_t* orow = h2 + (size_t)gw * F;
#pragma unroll
      for (int j = 0; j < 5; ++j) {
        int base2 = (lane & 48) + 64 * j;
        float o2 = bias;
#pragma unroll
        for (int c = 0; c < 16; ++c)
          o2 = fmaf(sx[base2 + c], w0[c], fmaf(sa[base2 + c], w1[c], o2));
        orow[lane + 64 * j] = f2bf(fmaxf(o2, 0.0f));
      }
    }
  }
  __threadfence();
  grid.sync();

  // ===== phase 4: tc2 GLU via MFMA + mean + linear head =====
  {
    const int quad = lane >> 4, hcol = lane & 15;
    short8 bfr[3][2];
#pragma unroll
    for (int tau = 0; tau < 3; ++tau)
#pragma unroll
      for (int s = 0; s < 2; ++s)
        bfr[tau][s] = *(const short8*)(Bf + (tau * 1024 + s * 512 + lane * 8));
    float pb = W[960 + hcol], qb = W[1744 + hcol], rb = W[2528 + hcol];
    float lw0 = W[3072 + 2 * hcol], lw1 = W[3073 + 2 * hcol];
    float ob0 = W[3104], ob1 = W[3105];
    int bm = hcol >> 3, t2m = hcol & 7;  // pair this lane loads (A rows)
    int kk0 = quad >> 1, off0 = (quad & 1) * 8;
    for (int grp = blockIdx.x; grp < Nn / 16; grp += gridDim.x) {
#pragma unroll
      for (int nn = 0; nn < 4; ++nn) {
        int n = grp * 16 + wid * 4 + nn;
        const ushort_t* row = h2 + (size_t)n * F;
        short8 a0 = *(const short8*)(row + (t2m + kk0) * 32 + bm * 16 + off0);
        short8 a1 = (short8)0;
        if (quad < 2) a1 = *(const short8*)(row + (t2m + 2) * 32 + bm * 16 + quad * 8);
        float4v accP = {0.f, 0.f, 0.f, 0.f};
        float4v accQ = {0.f, 0.f, 0.f, 0.f};
        float4v accR = {0.f, 0.f, 0.f, 0.f};
        accP = __builtin_amdgcn_mfma_f32_16x16x32_bf16(a0, bfr[0][0], accP, 0, 0, 0);
        accP = __builtin_amdgcn_mfma_f32_16x16x32_bf16(a1, bfr[0][1], accP, 0, 0, 0);
        accQ = __builtin_amdgcn_mfma_f32_16x16x32_bf16(a0, bfr[1][0], accQ, 0, 0, 0);
        accQ = __builtin_amdgcn_mfma_f32_16x16x32_bf16(a1, bfr[1][1], accQ, 0, 0, 0);
        accR = __builtin_amdgcn_mfma_f32_16x16x32_bf16(a0, bfr[2][0], accR, 0, 0, 0);
        accR = __builtin_amdgcn_mfma_f32_16x16x32_bf16(a1, bfr[2][1], accR, 0, 0, 0);
        float s0 = 0.0f;
#pragma unroll
        for (int r = 0; r < 4; ++r) {
          float P = accP[r] + pb, Q = accQ[r] + qb, R = accR[r] + rb;
          s0 += fmaxf(fmaf(P, sigm(Q), R), 0.0f);
        }
        s0 += __shfl_xor(s0, 16);  // quads {0,1}: b=0 over all 8 t2; {2,3}: b=1
        float mmean = s0 * 0.125f;
        float u0 = mmean * lw0, u1 = mmean * lw1;
#pragma unroll
        for (int d = 1; d < 16; d <<= 1) {
          u0 += __shfl_xor(u0, d);
          u1 += __shfl_xor(u1, d);
        }
        if ((lane & 31) == 0) {
          int b = lane >> 5;
          ((float2*)out)[(size_t)b * Nn + n] = make_float2(u0 + ob0, u1 + ob1);
        }
      }
    }
  }
}

// ---------------------------------------------------------------------------
extern "C" void kernel_launch(void* const* d_in, const int* in_sizes, int n_in,
                              void* d_out, int out_size, void* d_ws, size_t ws_size,
                              hipStream_t stream) {
  (void)in_sizes; (void)n_in; (void)out_size; (void)ws_size;
  const void* x = d_in[0];
  const void* ei = d_in[1];
  const void* ew = d_in[2];

  char* wsb = (char*)d_ws;
  size_t off = 0;
  auto alloc = [&](size_t bytes) -> void* {
    void* p = wsb + off;
    off = (off + bytes + 255) & ~(size_t)255;
    return p;
  };
  int* flags = (int*)alloc(256);
  float* W = (float*)alloc(4096 * 4);
  ushort_t* Bf = (ushort_t*)alloc(3072 * 2);               // tc2 B-fragments (bf16)
  uint_t* deg8 = (uint_t*)alloc((size_t)NXCD * NP * 4);    // fixed-point deg; copy0 becomes dis
  int* cnt8 = (int*)alloc((size_t)NXCD * NP * 4);          // contiguous after deg8 (zeroed together)
  uint_t* ecv8 = (uint_t*)alloc((size_t)NXCD * Nn * CAP8 * 4);  // per-XCD packed (src<<16|bf16 w)
  ushort_t* xfh = (ushort_t*)alloc((size_t)Nn * F * 2);    // h1 bf16 (f = t*32+b*16+h)
  ushort_t* h2 = (ushort_t*)alloc((size_t)Nn * F * 2);     // cheb output bf16
  float* outf = (float*)d_out;

  int zblk = (16 * NP + 255) / 256;  // block 0 also does detection + weights + Bf
  k_wprep<<<zblk, 256, 0, stream>>>(
      ew, ei,
      d_in[3], d_in[4], d_in[5], d_in[6], d_in[7], d_in[8],
      d_in[9], d_in[10], d_in[11], d_in[12], d_in[13], d_in[14],
      d_in[15], d_in[16], d_in[17], d_in[18], flags, W, Bf, deg8);

  // Cooperative mega-kernel: grid sized to guaranteed co-residency.
  int maxb = 0;
  if (hipOccupancyMaxActiveBlocksPerMultiprocessor(&maxb, k_mega, 256, 0) != hipSuccess || maxb < 1)
    maxb = 2;
  int grid = 256 * maxb;
  if (grid > 1024) grid = 1024;  // 4 blocks/CU cap; grid-stride handles any size
  void* ka[] = {(void*)&x,    (void*)&ei,   (void*)&ew,   (void*)&W,
                (void*)&flags, (void*)&xfh, (void*)&deg8, (void*)&cnt8,
                (void*)&ecv8, (void*)&h2,   (void*)&Bf,   (void*)&outf};
  hipLaunchCooperativeKernel((void*)k_mega, dim3(grid), dim3(256), ka, 0, stream);
}

// Round 5
// 278.042 us; speedup vs baseline: 2.5912x; 2.5912x over previous
//
#include <hip/hip_runtime.h>

typedef unsigned short ushort_t;
typedef unsigned int uint_t;
typedef __attribute__((ext_vector_type(8))) short short8;
typedef __attribute__((ext_vector_type(4))) float float4v;

constexpr int Bb = 2, Tt = 12, Nn = 50000, Hh = 16, Ee = 800000;
constexpr int T1 = 10, T2 = 8;
constexpr int F = 320;     // features per node, layout f = t*32 + b*16 + h
constexpr int NP = 50176;  // padded node stride for per-XCD deg/cnt copies
constexpr int NXCD = 8;    // MI355X XCD count
constexpr int CAP8 = 16;   // per-XCD bucket capacity per dst (8*16=128 total)

#define DEV __device__ __forceinline__

DEV float bf2f(ushort_t u) { return __uint_as_float(((uint_t)u) << 16); }
DEV ushort_t f2bf(float f) {
  uint_t u = __float_as_uint(f);
  u += 0x7fffu + ((u >> 16) & 1u);  // RNE
  return (ushort_t)(u >> 16);
}
DEV float blo(uint_t u) { return __uint_as_float(u << 16); }
DEV float bhi(uint_t u) { return __uint_as_float(u & 0xffff0000u); }
DEV float sigm(float x) { return 1.0f / (1.0f + __expf(-x)); }

// Hardware XCD id (0..7 on MI355X). Wave-uniform; partition hint only.
DEV int xcc_id() {
  int x;
  asm volatile("s_getreg_b32 %0, hwreg(HW_REG_XCC_ID)" : "=s"(x));
  return x & (NXCD - 1);
}

// Flag-aware loads: flags[0]=1 -> floats stored as bf16; flags[1]=1 -> ints are int64.
DEV float loadF(const void* p, int j, int isb) {
  return isb ? bf2f(((const ushort_t*)p)[j]) : ((const float*)p)[j];
}
DEV int loadI(const void* p, long long j, int is64) {
  return is64 ? (int)(((const long long*)p)[j]) : ((const int*)p)[j];
}

// ---------------------------------------------------------------------------
// Weight prep + dtype detection + workspace zeroing + tc2 B-fragment packing.
// W layout (float offsets):
//  tc1: Pw 0(48) Pb 48 Qw 64 Qb 112 Rw 128 Rb 176
//  tc2: Pw 192(768) Pb 960 Qw 976 Qb 1744 Rw 1760 Rb 2528
//  cheb: W0 2544(256) W1 2800(256) b 3056(16);  lin: W 3072(32) b 3104(2)
// Bf: tc2 weights as mfma_16x16x32_bf16 B-fragments (K=48 zero-padded to 64):
//  Bf[((tau*2+s)*64 + lane)*8 + j] = W_tau[s*32+(lane>>4)*8+j][lane&15].
// Zeroing covers deg8 (8*NP u32) + cnt8 (8*NP i32) = 16*NP contiguous words.
// ---------------------------------------------------------------------------
__global__ void k_wprep(const void* ew, const void* ei,
                        const void* t1Pw, const void* t1Pb,
                        const void* t1Qw, const void* t1Qb,
                        const void* t1Rw, const void* t1Rb,
                        const void* t2Pw, const void* t2Pb,
                        const void* t2Qw, const void* t2Qb,
                        const void* t2Rw, const void* t2Rb,
                        const void* chw, const void* chb,
                        const void* lw, const void* lb,
                        int* flags, float* W, ushort_t* Bf, uint_t* zero_base) {
  int gid = blockIdx.x * 256 + threadIdx.x;
  if (gid < 16 * NP) zero_base[gid] = 0u;
  if (blockIdx.x != 0) return;

  __shared__ int sflags[2];
  int tid = threadIdx.x;
  if (tid < 64) {
    int lane = tid;
    const ushort_t* u = (const ushort_t*)ew;
    int cnt = 0;
    for (int j = lane; j < 512; j += 64) cnt += (u[j] < 0x3F80u) ? 1 : 0;
#pragma unroll
    for (int d = 32; d; d >>= 1) cnt += __shfl_xor(cnt, d, 64);
    const int* e32 = (const int*)ei;
    int even_nz = 0, odd_nz = 0;
    for (int j = 2 * lane; j < 256; j += 128) {
      even_nz |= (e32[j] != 0);
      odd_nz |= (e32[j + 1] != 0);
    }
    unsigned long long be = __ballot(even_nz), bo = __ballot(odd_nz);
    if (lane == 0) {
      int f0 = (cnt >= 450) ? 1 : 0;
      int f1 = (bo == 0ull && be != 0ull) ? 1 : 0;
      sflags[0] = f0; sflags[1] = f1;
      flags[0] = f0; flags[1] = f1;
    }
  }
  __syncthreads();
  int isb = sflags[0];
#define CVT(src, off, n) for (int j = tid; j < (n); j += 256) W[(off) + j] = loadF(src, j, isb);
  CVT(t1Pw, 0, 48)   CVT(t1Pb, 48, 16)
  CVT(t1Qw, 64, 48)  CVT(t1Qb, 112, 16)
  CVT(t1Rw, 128, 48) CVT(t1Rb, 176, 16)
  CVT(t2Pw, 192, 768)  CVT(t2Pb, 960, 16)
  CVT(t2Qw, 976, 768)  CVT(t2Qb, 1744, 16)
  CVT(t2Rw, 1760, 768) CVT(t2Rb, 2528, 16)
  CVT(chw, 2544, 512)  CVT(chb, 3056, 16)
  CVT(lw, 3072, 32)    CVT(lb, 3104, 2)
#undef CVT
  // Pack tc2 weights into B-fragments (reads inputs directly; no W dependency).
  for (int i = tid; i < 3072; i += 256) {
    int j = i & 7, lane = (i >> 3) & 63, s = (i >> 9) & 1, tau = i >> 10;
    int kap = s * 32 + ((lane >> 4) << 3) + j;
    int nsub = lane & 15;
    ushort_t v = 0;
    if (kap < 48) {
      int kk = kap >> 4, c = kap & 15;
      const void* src = (tau == 0) ? t2Pw : (tau == 1) ? t2Qw : t2Rw;
      v = f2bf(loadF(src, kk * 256 + c * 16 + nsub, isb));
    }
    Bf[i] = v;
  }
}

// ---------------------------------------------------------------------------
// Fused tc1 + degree accumulation + bucket scatter (R1-proven 86.8 us form:
// 1 edge/thread — R16's 4-edge batch and R17's fat tc1 thread both regressed).
// ---------------------------------------------------------------------------
__global__ __launch_bounds__(256) void k_pre(const void* __restrict__ x,
                                             const void* __restrict__ ei,
                                             const void* __restrict__ ew,
                                             const float* __restrict__ W,
                                             const int* __restrict__ flags,
                                             ushort_t* __restrict__ xfh,
                                             uint_t* __restrict__ deg8,
                                             int* __restrict__ cnt8,
                                             uint_t* __restrict__ ecv8) {
  int id = blockIdx.x * 256 + threadIdx.x;
  int isb = flags[0];
  if (id < Ee) {
    int is64 = flags[1];
    int s = loadI(ei, id, is64), d = loadI(ei, (long long)Ee + id, is64);
    float w = loadF(ew, id, isb);
    int xcd = xcc_id();
    uint_t wq = __float2uint_rn(w * 16777216.0f);  // w * 2^24, w in [0,1]
    __hip_atomic_fetch_add(&deg8[xcd * NP + s], wq,
                           __ATOMIC_RELAXED, __HIP_MEMORY_SCOPE_WORKGROUP);
    int pos = __hip_atomic_fetch_add(&cnt8[xcd * NP + d], 1,
                                     __ATOMIC_RELAXED, __HIP_MEMORY_SCOPE_WORKGROUP);
    if (pos < CAP8)
      ecv8[((size_t)xcd * Nn + d) * CAP8 + pos] =
          ((uint_t)s << 16) | (uint_t)f2bf(w);
  }
  if (id < Bb * T1 * Nn) {
    int n = id % Nn;
    int bt = id / Nn;
    int t = bt % T1, b = bt / T1;
    float x0 = loadF(x, (b * Tt + t + 0) * Nn + n, isb);
    float x1 = loadF(x, (b * Tt + t + 1) * Nn + n, isb);
    float x2 = loadF(x, (b * Tt + t + 2) * Nn + n, isb);
    ushort_t g[16];
#pragma unroll
    for (int h = 0; h < 16; ++h) {
      float p = W[48 + h] + x0 * W[0 + h] + x1 * W[16 + h] + x2 * W[32 + h];
      float q = W[112 + h] + x0 * W[64 + h] + x1 * W[80 + h] + x2 * W[96 + h];
      float r = W[176 + h] + x0 * W[128 + h] + x1 * W[144 + h] + x2 * W[160 + h];
      g[h] = f2bf(fmaxf(fmaf(p, sigm(q), r), 0.0f));
    }
    uint_t u[8];
#pragma unroll
    for (int j = 0; j < 8; ++j) u[j] = (uint_t)g[2 * j] | ((uint_t)g[2 * j + 1] << 16);
    uint4* dst = (uint4*)(xfh + (size_t)n * F + t * 32 + b * 16);
    dst[0] = make_uint4(u[0], u[1], u[2], u[3]);
    dst[1] = make_uint4(u[4], u[5], u[6], u[7]);
  }
}

// ---------------------------------------------------------------------------
// Reduce the 8 fixed-point degree copies -> dis = 1/sqrt(deg), in place into
// copy 0 (as float).
// ---------------------------------------------------------------------------
__global__ __launch_bounds__(256) void k_dis(uint_t* __restrict__ deg8) {
  int i = blockIdx.x * 256 + threadIdx.x;
  if (i >= Nn) return;
  uint_t v = 0;
#pragma unroll
  for (int j = 0; j < 8; ++j) v += deg8[j * NP + i];
  float f = (float)v * (1.0f / 16777216.0f);
  ((float*)deg8)[i] = (v > 0u) ? (1.0f / sqrtf(fmaxf(f, 1e-12f))) : 0.0f;
}

// ---------------------------------------------------------------------------
// R19: Fused SpMM gather + Cheb combine + tc2 GLU (MFMA) + mean + head.
// One wave per dst node. The k_tc2h kernel read ONLY the h2 row this wave
// produces — block-local dataflow — so the h2 global round-trip (31 MB write
// + 32 MB read) and one kernel boundary are deleted: cheb output features go
// to wave-private LDS as bf16 (same f2bf rounding -> bit-identical values),
// A-fragments are read back from LDS, and the proven 6-MFMA GLU + mean +
// head epilogue stores out directly.
// ---------------------------------------------------------------------------
__global__ __launch_bounds__(256) void k_agg(const int* __restrict__ cnt8,
                                             const uint_t* __restrict__ ecv8,
                                             const float* __restrict__ dis,
                                             const uint2* __restrict__ xf2,
                                             const float* __restrict__ W,
                                             const ushort_t* __restrict__ Bf,
                                             float* __restrict__ out) {
  __shared__ float sh[4][640];       // per wave: [0..319]=agg, [320..639]=x
  __shared__ ushort_t sh2[4][320];   // per wave: cheb output features (bf16)
  int wid = threadIdx.x >> 6;
  int lane = threadIdx.x & 63;
  int gw = blockIdx.x * 4 + wid;
  // Merge 8 per-XCD sub-lists: prefix over counts, lane -> (xcd, slot).
  int myx = 0, slot = lane, tot = 0;
#pragma unroll
  for (int xx = 0; xx < NXCD; ++xx) {
    int c = min(cnt8[xx * NP + gw], CAP8);
    if (lane >= tot) { myx = xx; slot = lane - tot; }
    tot += c;
  }
  int deg = min(tot, 64);
  int l16 = 64 + (lane & 15);
  float a0 = 0.f, a1 = 0.f, a2 = 0.f, a3 = 0.f;
  float c0 = 0.f, c1 = 0.f, c2 = 0.f, c3 = 0.f;

#define ACC(v, p, q)                                                          \
  a0 = fmaf(v, blo(p.x), a0); a1 = fmaf(v, bhi(p.x), a1);                     \
  a2 = fmaf(v, blo(p.y), a2); a3 = fmaf(v, bhi(p.y), a3);                     \
  c0 = fmaf(v, blo(q.x), c0); c1 = fmaf(v, bhi(q.x), c1);                     \
  c2 = fmaf(v, blo(q.y), c2); c3 = fmaf(v, bhi(q.y), c3);

  int colv = 0;      // BYTE offset of this lane's src row
  int valv_i = 0;    // bits of val (for readlane broadcast)
  if (lane < deg) {
    uint_t t = ecv8[((size_t)myx * Nn + gw) * CAP8 + slot];
    int src = t >> 16;
    colv = src * (F * 2);
    valv_i = __float_as_int(bf2f((ushort_t)(t & 0xffffu)) * dis[src]);
  }
  const char* xb = (const char*)xf2;
  int e = 0;
  for (; e + 4 <= deg; e += 4) {
    int b0 = __builtin_amdgcn_readlane(colv, e + 0);
    int b1 = __builtin_amdgcn_readlane(colv, e + 1);
    int b2 = __builtin_amdgcn_readlane(colv, e + 2);
    int b3 = __builtin_amdgcn_readlane(colv, e + 3);
    float v0 = __int_as_float(__builtin_amdgcn_readlane(valv_i, e + 0));
    float v1 = __int_as_float(__builtin_amdgcn_readlane(valv_i, e + 1));
    float v2 = __int_as_float(__builtin_amdgcn_readlane(valv_i, e + 2));
    float v3 = __int_as_float(__builtin_amdgcn_readlane(valv_i, e + 3));
    const uint2* t0 = (const uint2*)(xb + b0);
    const uint2* t1 = (const uint2*)(xb + b1);
    const uint2* t2 = (const uint2*)(xb + b2);
    const uint2* t3 = (const uint2*)(xb + b3);
    uint2 p0 = t0[lane], q0 = t0[l16];
    uint2 p1 = t1[lane], q1 = t1[l16];
    uint2 p2 = t2[lane], q2 = t2[l16];
    uint2 p3 = t3[lane], q3 = t3[l16];
    ACC(v0, p0, q0) ACC(v1, p1, q1) ACC(v2, p2, q2) ACC(v3, p3, q3)
  }
  for (; e < deg; ++e) {
    int b = __builtin_amdgcn_readlane(colv, e);
    float v = __int_as_float(__builtin_amdgcn_readlane(valv_i, e));
    const uint2* tp = (const uint2*)(xb + b);
    uint2 p = tp[lane], q = tp[l16];
    ACC(v, p, q)
  }
#undef ACC

  float nd = -dis[gw];  // wave-uniform
  float* sa = sh[wid];
  float* sx = sh[wid] + 320;
  const uint2* xrow = xf2 + (size_t)gw * 80;
  uint2 xp = xrow[lane], xq = xrow[l16];
  ((float4*)sa)[lane] = make_float4(a0 * nd, a1 * nd, a2 * nd, a3 * nd);
  ((float4*)sx)[lane] = make_float4(blo(xp.x), bhi(xp.x), blo(xp.y), bhi(xp.y));
  if (lane < 16) {
    ((float4*)sa)[64 + lane] = make_float4(c0 * nd, c1 * nd, c2 * nd, c3 * nd);
    ((float4*)sx)[64 + lane] = make_float4(blo(xq.x), bhi(xq.x), blo(xq.y), bhi(xq.y));
  }
  __builtin_amdgcn_wave_barrier();  // wave-private LDS: block compiler reordering only
  int h = lane & 15;
  {
    float w0[16], w1[16];
#pragma unroll
    for (int c = 0; c < 16; ++c) {
      w0[c] = W[2544 + c * 16 + h];
      w1[c] = W[2800 + c * 16 + h];
    }
    float bias = W[3056 + h];
    ushort_t* s2 = sh2[wid];
#pragma unroll
    for (int j = 0; j < 5; ++j) {
      int base2 = (lane & 48) + 64 * j;
      float o2 = bias;
#pragma unroll
      for (int c = 0; c < 16; ++c)
        o2 = fmaf(sx[base2 + c], w0[c], fmaf(sa[base2 + c], w1[c], o2));
      s2[lane + 64 * j] = f2bf(fmaxf(o2, 0.0f));
    }
  }
  __builtin_amdgcn_wave_barrier();

  // ===== tc2 GLU via MFMA + mean + linear head (this node only) =====
  // A-frag: lane m=lane&15 (=(b,t2) pair), k=quad*8+j -> 16 B LDS reads.
  // C/D: col=lane&15 (=h), row=quad*4+reg (=pair); quads 0,1 b=0, 2,3 b=1.
  {
    const ushort_t* s2 = sh2[wid];
    int quad = lane >> 4, hcol = h;
    int bm = hcol >> 3, t2m = hcol & 7;   // pair this lane loads (A rows)
    int kk0 = quad >> 1, off0 = (quad & 1) * 8;
    short8 a0f = *(const short8*)(s2 + (t2m + kk0) * 32 + bm * 16 + off0);
    short8 a1f = (short8)0;
    if (quad < 2) a1f = *(const short8*)(s2 + (t2m + 2) * 32 + bm * 16 + quad * 8);
    short8 bfr[3][2];
#pragma unroll
    for (int tau = 0; tau < 3; ++tau)
#pragma unroll
      for (int s = 0; s < 2; ++s)
        bfr[tau][s] = *(const short8*)(Bf + (tau * 1024 + s * 512 + lane * 8));
    float pb = W[960 + hcol], qb = W[1744 + hcol], rb = W[2528 + hcol];
    float lw0 = W[3072 + 2 * hcol], lw1 = W[3073 + 2 * hcol];
    float ob0 = W[3104], ob1 = W[3105];
    float4v accP = {0.f, 0.f, 0.f, 0.f};
    float4v accQ = {0.f, 0.f, 0.f, 0.f};
    float4v accR = {0.f, 0.f, 0.f, 0.f};
    accP = __builtin_amdgcn_mfma_f32_16x16x32_bf16(a0f, bfr[0][0], accP, 0, 0, 0);
    accP = __builtin_amdgcn_mfma_f32_16x16x32_bf16(a1f, bfr[0][1], accP, 0, 0, 0);
    accQ = __builtin_amdgcn_mfma_f32_16x16x32_bf16(a0f, bfr[1][0], accQ, 0, 0, 0);
    accQ = __builtin_amdgcn_mfma_f32_16x16x32_bf16(a1f, bfr[1][1], accQ, 0, 0, 0);
    accR = __builtin_amdgcn_mfma_f32_16x16x32_bf16(a0f, bfr[2][0], accR, 0, 0, 0);
    accR = __builtin_amdgcn_mfma_f32_16x16x32_bf16(a1f, bfr[2][1], accR, 0, 0, 0);
    float s0 = 0.0f;
#pragma unroll
    for (int r = 0; r < 4; ++r) {
      float P = accP[r] + pb, Q = accQ[r] + qb, R = accR[r] + rb;
      s0 += fmaxf(fmaf(P, sigm(Q), R), 0.0f);
    }
    s0 += __shfl_xor(s0, 16);   // quads {0,1}: b=0 over all 8 t2; {2,3}: b=1
    float mmean = s0 * 0.125f;
    float u0 = mmean * lw0, u1 = mmean * lw1;
#pragma unroll
    for (int d = 1; d < 16; d <<= 1) {
      u0 += __shfl_xor(u0, d);
      u1 += __shfl_xor(u1, d);
    }
    if ((lane & 31) == 0) {
      int b = lane >> 5;
      ((float2*)out)[(size_t)b * Nn + gw] = make_float2(u0 + ob0, u1 + ob1);
    }
  }
}

// ---------------------------------------------------------------------------
extern "C" void kernel_launch(void* const* d_in, const int* in_sizes, int n_in,
                              void* d_out, int out_size, void* d_ws, size_t ws_size,
                              hipStream_t stream) {
  (void)in_sizes; (void)n_in; (void)out_size; (void)ws_size;
  const void* x = d_in[0];
  const void* ei = d_in[1];
  const void* ew = d_in[2];

  char* wsb = (char*)d_ws;
  size_t off = 0;
  auto alloc = [&](size_t bytes) -> void* {
    void* p = wsb + off;
    off = (off + bytes + 255) & ~(size_t)255;
    return p;
  };
  int* flags = (int*)alloc(256);
  float* W = (float*)alloc(4096 * 4);
  ushort_t* Bf = (ushort_t*)alloc(3072 * 2);               // tc2 B-fragments (bf16)
  uint_t* deg8 = (uint_t*)alloc((size_t)NXCD * NP * 4);    // fixed-point deg; copy0 becomes dis
  int* cnt8 = (int*)alloc((size_t)NXCD * NP * 4);          // contiguous after deg8 (zeroed together)
  uint_t* ecv8 = (uint_t*)alloc((size_t)NXCD * Nn * CAP8 * 4);  // per-XCD packed (src<<16|bf16 w)
  ushort_t* xfh = (ushort_t*)alloc((size_t)Nn * F * 2);    // h1 bf16 (f = t*32+b*16+h)
  // total ~61 MB of d_ws (h2 eliminated)

  int zblk = (16 * NP + 255) / 256;  // block 0 also does detection + weights + Bf
  k_wprep<<<zblk, 256, 0, stream>>>(
      ew, ei,
      d_in[3], d_in[4], d_in[5], d_in[6], d_in[7], d_in[8],
      d_in[9], d_in[10], d_in[11], d_in[12], d_in[13], d_in[14],
      d_in[15], d_in[16], d_in[17], d_in[18], flags, W, Bf, deg8);

  k_pre<<<(Bb * T1 * Nn + 255) / 256, 256, 0, stream>>>(x, ei, ew, W, flags, xfh, deg8, cnt8, ecv8);
  k_dis<<<(Nn + 255) / 256, 256, 0, stream>>>(deg8);
  k_agg<<<Nn / 4, 256, 0, stream>>>(cnt8, ecv8, (const float*)deg8, (const uint2*)xfh, W, Bf,
                                    (float*)d_out);
}